// Round 1
// baseline (17332.411 us; speedup 1.0000x reference)
//
#include <hip/hip_runtime.h>
#include <math.h>

#define NB 4
#define SEQ 1024
#define DIM 768
#define NH 12
#define HD 64
#define FF 3072
#define NL 12
#define VOCAB 50257
#define NTOK 4096   // NB*SEQ

typedef unsigned short u16;
typedef __attribute__((ext_vector_type(8))) short short8;   // 8 bf16 (guide-verified frag type)
typedef __attribute__((ext_vector_type(4))) float floatx4;

__device__ __forceinline__ u16 f2bf(float f) {
  union { float f; unsigned u; } v; v.f = f;
  unsigned u = v.u;
  u += 0x7fffu + ((u >> 16) & 1u);   // RNE
  return (u16)(u >> 16);
}

// ---------------- embedding: x[row] = tok[id] + pos[s] ----------------
__global__ __launch_bounds__(256) void embed_kernel(const int* __restrict__ ids,
                                                    const float* __restrict__ tok,
                                                    const float* __restrict__ pos,
                                                    float* __restrict__ x) {
  int row = blockIdx.x;
  int s = row & (SEQ - 1);
  int id = ids[row];
  const float* te = tok + (size_t)id * DIM;
  const float* pe = pos + (size_t)s * DIM;
  float* xr = x + (size_t)row * DIM;
  for (int d = threadIdx.x; d < DIM; d += 256) xr[d] = te[d] + pe[d];
}

// ---------------- layernorm: fp32 in -> bf16 out ----------------
__global__ __launch_bounds__(256) void ln_kernel(const float* __restrict__ x,
                                                 const float* __restrict__ g,
                                                 const float* __restrict__ b,
                                                 u16* __restrict__ out) {
  int row = blockIdx.x;
  const float* xr = x + (size_t)row * DIM;
  int t = threadIdx.x;
  float v0 = xr[t], v1 = xr[t + 256], v2 = xr[t + 512];
  float s = v0 + v1 + v2;
  float s2 = v0*v0 + v1*v1 + v2*v2;
  #pragma unroll
  for (int off = 32; off; off >>= 1) { s += __shfl_xor(s, off); s2 += __shfl_xor(s2, off); }
  __shared__ float rs[4], rs2[4];
  int wave = t >> 6;
  if ((t & 63) == 0) { rs[wave] = s; rs2[wave] = s2; }
  __syncthreads();
  s = rs[0] + rs[1] + rs[2] + rs[3];
  s2 = rs2[0] + rs2[1] + rs2[2] + rs2[3];
  float mean = s * (1.f / DIM);
  float var = s2 * (1.f / DIM) - mean * mean;
  float rstd = rsqrtf(var + 1e-5f);
  u16* orow = out + (size_t)row * DIM;
  orow[t]       = f2bf(g[t]       * ((v0 - mean) * rstd) + b[t]);
  orow[t + 256] = f2bf(g[t + 256] * ((v1 - mean) * rstd) + b[t + 256]);
  orow[t + 512] = f2bf(g[t + 512] * ((v2 - mean) * rstd) + b[t + 512]);
}

// ---------------- weight prep: fp32 [K,N] -> bf16 [N,K], batched over layers ----------------
__global__ __launch_bounds__(256) void transpose_cast_kernel(const float* __restrict__ in,
                                                             u16* __restrict__ out, int K, int N) {
  __shared__ float tile[64][65];
  size_t off = (size_t)blockIdx.z * K * N;
  in += off; out += off;
  int k0 = blockIdx.y * 64, n0 = blockIdx.x * 64;
  int t = threadIdx.x;
  #pragma unroll
  for (int i = 0; i < 4; i++) {
    int idx = t + 256 * i;
    int r = idx >> 4, c = (idx & 15) * 4;
    float4 v = *(const float4*)&in[(size_t)(k0 + r) * N + n0 + c];
    tile[r][c] = v.x; tile[r][c+1] = v.y; tile[r][c+2] = v.z; tile[r][c+3] = v.w;
  }
  __syncthreads();
  #pragma unroll
  for (int i = 0; i < 4; i++) {
    int idx = t + 256 * i;
    int rn = idx >> 4, ck = (idx & 15) * 4;
    ushort4 o;
    o.x = f2bf(tile[ck+0][rn]); o.y = f2bf(tile[ck+1][rn]);
    o.z = f2bf(tile[ck+2][rn]); o.w = f2bf(tile[ck+3][rn]);
    *(ushort4*)&out[(size_t)(n0 + rn) * K + k0 + ck] = o;
  }
}

// ---------------- plain fp32 -> bf16 cast (tok_embed for lm_head) ----------------
__global__ __launch_bounds__(256) void cast_bf16_kernel(const float* __restrict__ in,
                                                        u16* __restrict__ out, long n4) {
  long i = (long)blockIdx.x * 256 + threadIdx.x;
  if (i >= n4) return;
  float4 v = ((const float4*)in)[i];
  ushort4 o; o.x = f2bf(v.x); o.y = f2bf(v.y); o.z = f2bf(v.z); o.w = f2bf(v.w);
  ((ushort4*)out)[i] = o;
}

// ---------------- GEMM: C[M,N] = A[M,K](bf16) * Bt[N,K](bf16)^T + epilogue ----------------
// EPI: 0=none, 1=+bias, 2=+bias+resid, 3=+bias+gelu.  OUTBF: bf16 out if 1 else fp32.
template<int EPI, int OUTBF>
__global__ __launch_bounds__(256) void gemm_bt(const u16* __restrict__ A,
                                               const u16* __restrict__ Bt,
                                               const float* __restrict__ bias,
                                               const float* __restrict__ resid,
                                               float* __restrict__ outF,
                                               u16* __restrict__ outB,
                                               int M, int N, int K) {
  __shared__ u16 As[128 * 40];
  __shared__ u16 Bs[128 * 40];
  const int t = threadIdx.x;
  const int m0 = blockIdx.y * 128, n0 = blockIdx.x * 128;
  const int lane = t & 63, wave = t >> 6;
  const int wm = (wave >> 1) * 64, wn = (wave & 1) * 64;
  const int l15 = lane & 15, quad = lane >> 4;

  floatx4 acc[4][4];
  #pragma unroll
  for (int i = 0; i < 4; i++)
    #pragma unroll
    for (int j = 0; j < 4; j++) { floatx4 z = {0.f, 0.f, 0.f, 0.f}; acc[i][j] = z; }

  for (int k0 = 0; k0 < K; k0 += 32) {
    #pragma unroll
    for (int i = 0; i < 2; i++) {
      int idx = t + 256 * i;
      int row = idx >> 2, c8 = (idx & 3) << 3;
      *(uint4*)&As[row * 40 + c8] = *(const uint4*)&A[(size_t)(m0 + row) * K + k0 + c8];
      int nr = n0 + row;
      uint4 bv = {0u, 0u, 0u, 0u};
      if (nr < N) bv = *(const uint4*)&Bt[(size_t)nr * K + k0 + c8];
      *(uint4*)&Bs[row * 40 + c8] = bv;
    }
    __syncthreads();
    short8 af[4], bfr[4];
    #pragma unroll
    for (int mi = 0; mi < 4; mi++) af[mi] = *(const short8*)&As[(wm + mi * 16 + l15) * 40 + quad * 8];
    #pragma unroll
    for (int ni = 0; ni < 4; ni++) bfr[ni] = *(const short8*)&Bs[(wn + ni * 16 + l15) * 40 + quad * 8];
    #pragma unroll
    for (int mi = 0; mi < 4; mi++)
      #pragma unroll
      for (int ni = 0; ni < 4; ni++)
        acc[mi][ni] = __builtin_amdgcn_mfma_f32_16x16x32_bf16(af[mi], bfr[ni], acc[mi][ni], 0, 0, 0);
    __syncthreads();
  }

  #pragma unroll
  for (int mi = 0; mi < 4; mi++) {
    #pragma unroll
    for (int ni = 0; ni < 4; ni++) {
      int gc = n0 + wn + ni * 16 + l15;
      if (gc >= N) continue;
      #pragma unroll
      for (int r = 0; r < 4; r++) {
        int gr = m0 + wm + mi * 16 + quad * 4 + r;
        float v = acc[mi][ni][r];
        if (EPI >= 1) v += bias[gc];
        if (EPI == 2) v += resid[(size_t)gr * N + gc];
        if (EPI == 3) {
          float u = 0.7978845608028654f * (v + 0.044715f * v * v * v);
          v = 0.5f * v * (1.f + tanhf(u));
        }
        size_t o = (size_t)gr * N + gc;
        if (OUTBF) outB[o] = f2bf(v); else outF[o] = v;
      }
    }
  }
}

// ---------------- fp32 flash attention: qkv [NTOK, 3*DIM] -> out bf16 [NTOK, DIM] ----------------
__global__ __launch_bounds__(256) void attn_kernel(const float* __restrict__ qkv,
                                                   u16* __restrict__ out) {
  __shared__ float Qs[64 * 68];
  __shared__ float KVs[64 * 68];
  __shared__ float Ps[64 * 68];
  const int qb = blockIdx.x;            // q-tile (0..15)
  const int bh = blockIdx.y;            // b*NH + h
  const int bb = bh / NH, hh = bh % NH;
  const int rowBase = bb * SEQ;
  const int q0 = qb * 64;
  const int t = threadIdx.x, lane = t & 63, wid = t >> 6;
  const int rw = wid * 16;              // wave's first q-row within tile

  #pragma unroll
  for (int i = 0; i < 4; i++) {         // stage Q tile
    int idx = t + 256 * i;
    int r = idx >> 4, c = (idx & 15) * 4;
    float4 v = *(const float4*)&qkv[(size_t)(rowBase + q0 + r) * 2304 + hh * 64 + c];
    *(float4*)&Qs[r * 68 + c] = v;
  }

  float m_i[16], l_i[16], o_i[16];
  #pragma unroll
  for (int r = 0; r < 16; r++) { m_i[r] = -1e30f; l_i[r] = 0.f; o_i[r] = 0.f; }

  for (int kt = 0; kt <= qb; kt++) {
    __syncthreads();                    // protect KVs from previous phase-B readers
    #pragma unroll
    for (int i = 0; i < 4; i++) {       // stage K tile
      int idx = t + 256 * i;
      int r = idx >> 4, c = (idx & 15) * 4;
      float4 v = *(const float4*)&qkv[(size_t)(rowBase + kt * 64 + r) * 2304 + 768 + hh * 64 + c];
      *(float4*)&KVs[r * 68 + c] = v;
    }
    __syncthreads();

    float4 kreg[16];                    // this lane's key row in registers
    const float4* kr = (const float4*)&KVs[lane * 68];
    #pragma unroll
    for (int dd = 0; dd < 16; dd++) kreg[dd] = kr[dd];
    const int kg = kt * 64 + lane;

    #pragma unroll
    for (int r = 0; r < 16; r++) {      // scores + online softmax
      const float4* qr = (const float4*)&Qs[(rw + r) * 68];
      float s = 0.f;
      #pragma unroll
      for (int dd = 0; dd < 16; dd++) {
        float4 q4 = qr[dd];
        s += q4.x * kreg[dd].x + q4.y * kreg[dd].y + q4.z * kreg[dd].z + q4.w * kreg[dd].w;
      }
      s *= 0.125f;
      if (kg > q0 + rw + r) s = -1e30f; // causal mask (only bites on diagonal tile)
      float mx = s;
      #pragma unroll
      for (int off = 32; off; off >>= 1) mx = fmaxf(mx, __shfl_xor(mx, off));
      float mnew = fmaxf(m_i[r], mx);
      float p = __expf(s - mnew);
      float alpha = __expf(m_i[r] - mnew);
      float sum = p;
      #pragma unroll
      for (int off = 32; off; off >>= 1) sum += __shfl_xor(sum, off);
      l_i[r] = l_i[r] * alpha + sum;
      m_i[r] = mnew;
      o_i[r] *= alpha;
      Ps[(rw + r) * 68 + lane] = p;
    }
    __syncthreads();
    #pragma unroll
    for (int i = 0; i < 4; i++) {       // stage V tile (overwrite K buffer)
      int idx = t + 256 * i;
      int r = idx >> 4, c = (idx & 15) * 4;
      float4 v = *(const float4*)&qkv[(size_t)(rowBase + kt * 64 + r) * 2304 + 1536 + hh * 64 + c];
      *(float4*)&KVs[r * 68 + c] = v;
    }
    __syncthreads();

    float vreg[64];                     // this lane's output-dim column of V
    #pragma unroll
    for (int j = 0; j < 64; j++) vreg[j] = KVs[j * 68 + lane];
    #pragma unroll
    for (int r = 0; r < 16; r++) {      // O += P * V
      const float4* pr = (const float4*)&Ps[(rw + r) * 68];
      float acc = 0.f;
      #pragma unroll
      for (int dd = 0; dd < 16; dd++) {
        float4 p4 = pr[dd];
        acc += p4.x * vreg[dd*4] + p4.y * vreg[dd*4+1] + p4.z * vreg[dd*4+2] + p4.w * vreg[dd*4+3];
      }
      o_i[r] += acc;
    }
  }

  #pragma unroll
  for (int r = 0; r < 16; r++) {
    int row = rowBase + q0 + rw + r;
    out[(size_t)row * DIM + hh * 64 + lane] = f2bf(o_i[r] / l_i[r]);
  }
}

// =======================================================================
extern "C" void kernel_launch(void* const* d_in, const int* in_sizes, int n_in,
                              void* d_out, int out_size, void* d_ws, size_t ws_size,
                              hipStream_t stream) {
  const int*   ids  = (const int*)d_in[0];
  const float* tokE = (const float*)d_in[1];
  const float* posE = (const float*)d_in[2];
  const float* ln1g = (const float*)d_in[3];
  const float* ln1b = (const float*)d_in[4];
  const float* qkvw = (const float*)d_in[5];
  const float* qkvb = (const float*)d_in[6];
  const float* outw = (const float*)d_in[7];
  const float* outb = (const float*)d_in[8];
  const float* ln2g = (const float*)d_in[9];
  const float* ln2b = (const float*)d_in[10];
  const float* fc1w = (const float*)d_in[11];
  const float* fc1b = (const float*)d_in[12];
  const float* fc2w = (const float*)d_in[13];
  const float* fc2b = (const float*)d_in[14];
  const float* lnfg = (const float*)d_in[15];
  const float* lnfb = (const float*)d_in[16];
  float* logits = (float*)d_out;

  char* ws = (char*)d_ws;
  size_t off = 0;
  auto alloc = [&](size_t bytes) { void* p = ws + off; off += (bytes + 255) & ~(size_t)255; return p; };
  u16*   wt_qkv = (u16*)alloc((size_t)NL * 2304 * 768 * 2);
  u16*   wt_out = (u16*)alloc((size_t)NL * 768 * 768 * 2);
  u16*   wt_fc1 = (u16*)alloc((size_t)NL * 3072 * 768 * 2);
  u16*   wt_fc2 = (u16*)alloc((size_t)NL * 768 * 3072 * 2);
  u16*   tokEb  = (u16*)alloc((size_t)VOCAB * 768 * 2);
  float* x      = (float*)alloc((size_t)NTOK * 768 * 4);
  u16*   h      = (u16*)alloc((size_t)NTOK * 768 * 2);
  float* qkvbuf = (float*)alloc((size_t)NTOK * 2304 * 4);
  u16*   attnb  = (u16*)alloc((size_t)NTOK * 768 * 2);
  u16*   ffh    = (u16*)alloc((size_t)NTOK * 3072 * 2);

  // ---- weight prep (every call: ws is re-poisoned) ----
  transpose_cast_kernel<<<dim3(36, 12, NL), 256, 0, stream>>>(qkvw, wt_qkv, 768, 2304);
  transpose_cast_kernel<<<dim3(12, 12, NL), 256, 0, stream>>>(outw, wt_out, 768, 768);
  transpose_cast_kernel<<<dim3(48, 12, NL), 256, 0, stream>>>(fc1w, wt_fc1, 768, 3072);
  transpose_cast_kernel<<<dim3(12, 48, NL), 256, 0, stream>>>(fc2w, wt_fc2, 3072, 768);
  long n4 = (long)VOCAB * 768 / 4;
  cast_bf16_kernel<<<(int)((n4 + 255) / 256), 256, 0, stream>>>(tokE, tokEb, n4);

  // ---- embedding ----
  embed_kernel<<<NTOK, 256, 0, stream>>>(ids, tokE, posE, x);

  // ---- transformer blocks ----
  for (int l = 0; l < NL; l++) {
    ln_kernel<<<NTOK, 256, 0, stream>>>(x, ln1g + l * 768, ln1b + l * 768, h);
    gemm_bt<1, 0><<<dim3(18, 32), 256, 0, stream>>>(h, wt_qkv + (size_t)l * 2304 * 768,
        qkvb + l * 2304, nullptr, qkvbuf, nullptr, NTOK, 2304, 768);
    attn_kernel<<<dim3(16, NB * NH), 256, 0, stream>>>(qkvbuf, attnb);
    gemm_bt<2, 0><<<dim3(6, 32), 256, 0, stream>>>(attnb, wt_out + (size_t)l * 768 * 768,
        outb + l * 768, x, x, nullptr, NTOK, 768, 768);
    ln_kernel<<<NTOK, 256, 0, stream>>>(x, ln2g + l * 768, ln2b + l * 768, h);
    gemm_bt<3, 1><<<dim3(24, 32), 256, 0, stream>>>(h, wt_fc1 + (size_t)l * 3072 * 768,
        fc1b + l * 3072, nullptr, nullptr, ffh, NTOK, 3072, 768);
    gemm_bt<2, 0><<<dim3(6, 32), 256, 0, stream>>>(ffh, wt_fc2 + (size_t)l * 768 * 3072,
        fc2b + l * 768, x, x, nullptr, NTOK, 768, 3072);
  }

  // ---- final LN + tied lm_head ----
  ln_kernel<<<NTOK, 256, 0, stream>>>(x, lnfg, lnfb, h);
  gemm_bt<0, 0><<<dim3((VOCAB + 127) / 128, 32), 256, 0, stream>>>(h, tokEb,
      nullptr, nullptr, logits, nullptr, NTOK, VOCAB, 768);
}